// Round 3
// baseline (441.309 us; speedup 1.0000x reference)
//
#include <hip/hip_runtime.h>
#include <stdint.h>

// ---------------------------------------------------------------------------
// MeshGraphNets edge processor, round 3.
//   gather+concat(384) -> 128 relu -> 128 relu -> 128 -> LayerNorm, E=320000.
//
// Round-3 changes vs round 2 (which was latency-bound: Mfma 10%, VALU 8%,
// HBM 34%, everything idle):
//  * T3/T4: raw s_barrier + COUNTED s_waitcnt vmcnt(N) (never 0 in the main
//    loop). 3-deep LDS ring, stage issue-ahead 2. VMEM issue order pinned
//    with compiler fences so N is statically known; undercount = safe.
//  * 5-slot rolling gather window, issued kstep(t) -> XISSUE(t+5), no longer
//    force-drained at barriers -> ~500cy latency cover for x gathers.
//  * Epilogue: wave-private LDS transpose ([32][33] f32, (row+col)%32 banks)
//    so every global store instr covers 16 rows x 64B contiguous. Round 2's
//    32B-per-row stores caused 1.95x write amplification (312MB vs 160MB).
//  * Biases/gamma/beta staged into LDS in the prologue (compute regions have
//    ZERO VMEM so the vmcnt arithmetic stays exact).
// ---------------------------------------------------------------------------

typedef __attribute__((ext_vector_type(8)))  short    s16x8;
typedef __attribute__((ext_vector_type(8)))  _Float16 f16x8;
typedef __attribute__((ext_vector_type(16))) float    f32x16;
typedef __attribute__((ext_vector_type(4)))  float    f32x4;

#define FENCE asm volatile("" ::: "memory")
#define VMWAIT(N) asm volatile("s_waitcnt vmcnt(" #N ")" ::: "memory")
#define BARRIER do { __builtin_amdgcn_s_barrier(); asm volatile("" ::: "memory"); } while (0)

__device__ __forceinline__ f32x16 mfma16(f16x8 a, f16x8 b, f32x16 c) {
  return __builtin_amdgcn_mfma_f32_32x32x16_f16(a, b, c, 0, 0, 0);
}

// ---------------------------------------------------------------------------
// prep: W0[384][128], W1[128][128], W2[128][128] (fp32, k-major) -> fp16
// transposed swizzled slab images in d_ws (identical to round 2, verified).
// ---------------------------------------------------------------------------
__global__ void prep_weights(const float* __restrict__ W0,
                             const float* __restrict__ W1,
                             const float* __restrict__ W2,
                             short* __restrict__ ws) {
  int tid = blockIdx.x * 256 + threadIdx.x;        // 10240 threads
  const float* W;
  int rel, imgbase, perm;
  if (tid < 6144)      { W = W0; rel = tid;        imgbase = 0;     perm = 0; }
  else if (tid < 8192) { W = W1; rel = tid - 6144; imgbase = 49152; perm = 1; }
  else                 { W = W2; rel = tid - 8192; imgbase = 65536; perm = 1; }
  int n     = rel & 127;
  int chunk = rel >> 7;       // slab*8 + kc
  int slab  = chunk >> 3;
  int kc    = chunk & 7;
  s16x8 o;
#pragma unroll
  for (int j = 0; j < 8; ++j) {
    int kslot = slab * 64 + kc * 8 + j;
    int ktrue = perm ? ((kslot & ~12) | ((kslot & 4) << 1) | ((kslot & 8) >> 1))
                     : kslot;
    float v = W[(size_t)ktrue * 128 + n];
    o[j] = __builtin_bit_cast(short, (_Float16)v);
  }
  *(s16x8*)(ws + imgbase + slab * 8192 + n * 64 + ((kc ^ (n & 7)) << 3)) = o;
}

// Stage slab s (16KB) into LDS ring slot (linear dest, pre-swizzled source).
__device__ __forceinline__ void stage(const short* __restrict__ ws, int s,
                                      int slot, char* lds, int tid) {
  char* buf = lds + slot * 16384;
  const char* g = (const char*)ws + s * 16384;
#pragma unroll
  for (int i = 0; i < 2; ++i) {
    char* lp = buf + (i * 512 + (tid & ~63)) * 16;   // wave-uniform base
    const char* gp = g + (i * 512 + tid) * 16;       // per-lane source
    __builtin_amdgcn_global_load_lds(
        (__attribute__((address_space(1))) const void*)gp,
        (__attribute__((address_space(3))) void*)lp, 16, 0, 0);
  }
}

// One K=16 step: 4 output tiles, A = W^T fragment from swizzled LDS,
// B = xf (lane-resident activations).
__device__ __forceinline__ void kstep(const char* buf, int q, int lg1,
                                      int e31, f16x8 xf, f32x16* acc) {
  const int kc = q * 2 + lg1;
  const int slot = (kc ^ (e31 & 7)) << 4;
#pragma unroll
  for (int nt = 0; nt < 4; ++nt) {
    int n = nt * 32 + e31;
    s16x8 wf = *(const s16x8*)(buf + n * 128 + slot);
    acc[nt] = mfma16(__builtin_bit_cast(f16x8, wf), xf, acc[nt]);
  }
}

// bias + relu + cvt to fp16 B-fragments (bias read from LDS; broadcast).
__device__ __forceinline__ void transition(const float* __restrict__ b,
                                           int lg1, f32x16* acc, f16x8* fr) {
#pragma unroll
  for (int ks = 0; ks < 8; ++ks) {
    const int nt = ks >> 1;
#pragma unroll
    for (int jq = 0; jq < 2; ++jq) {
      int nb = nt * 32 + 16 * (ks & 1) + 8 * jq + 4 * lg1;
      f32x4 bv = *(const f32x4*)(b + nb);
#pragma unroll
      for (int r = 0; r < 4; ++r) {
        float h = acc[nt][8 * (ks & 1) + jq * 4 + r] + bv[r];
        fr[ks][jq * 4 + r] = (_Float16)fmaxf(h, 0.0f);
      }
    }
  }
}

__device__ __forceinline__ void zero_acc(f32x16* acc) {
#pragma unroll
  for (int nt = 0; nt < 4; ++nt)
#pragma unroll
    for (int i = 0; i < 16; ++i) acc[nt][i] = 0.0f;
}

__global__ __launch_bounds__(512, 4) void edge_mlp(
    const float* __restrict__ sf, const float* __restrict__ rf,
    const float* __restrict__ ef, const int* __restrict__ snd,
    const int* __restrict__ rcv, const short* __restrict__ wt,
    const float* __restrict__ b0, const float* __restrict__ b1,
    const float* __restrict__ b2, const float* __restrict__ gamma,
    const float* __restrict__ beta, float* __restrict__ out) {
  // [0,49152): 3x16KB weight ring (also reused as transpose buf in epilogue)
  // [49152,52224): params b0|b1|b2|gamma|beta(+pad), 512B each
  __shared__ __align__(16) char lds[52224];
  const int tid  = threadIdx.x;
  const int w    = tid >> 6;
  const int lane = tid & 63;
  const int e31  = lane & 31;
  const int lg1  = lane >> 5;
  const int eb   = blockIdx.x * 256 + w * 32;
  const int e    = eb + e31;

  // ---- prologue: params -> LDS, idx loads, slabs 0&1, x window 0..4 ----
  if (w < 3) {
    const float* s0 = (w == 0) ? b0 : (w == 1) ? b2 : beta;
    const float* s1 = (w == 0) ? b1 : (w == 1) ? gamma : beta;
    const float* src = ((lane < 32) ? s0 : s1) + (lane & 31) * 4;
    char* dst = lds + 49152 + w * 1024;   // wave-uniform base
    __builtin_amdgcn_global_load_lds(
        (__attribute__((address_space(1))) const void*)src,
        (__attribute__((address_space(3))) void*)dst, 16, 0, 0);
  }
  FENCE;
  const int sidx = snd[e];
  const int ridx = rcv[e];
  FENCE;
  stage(wt, 0, 0, lds, tid);
  FENCE;
  stage(wt, 1, 1, lds, tid);
  FENCE;

  const float* xbase0 = sf + (size_t)sidx * 128 + lg1 * 8;
  const float* xbase1 = rf + (size_t)ridx * 128 + lg1 * 8;
  const float* xbase2 = ef + (size_t)e    * 128 + lg1 * 8;
#define XPTR(t) ((t) < 8 ? xbase0 + (t) * 16 \
                : (t) < 16 ? xbase1 + ((t) - 8) * 16 \
                : xbase2 + ((t) - 16) * 16)
#define XISSUE(t) do { const float* p_ = XPTR(t); \
    xa[(t) % 5] = *(const f32x4*)p_; xb[(t) % 5] = *(const f32x4*)(p_ + 4); } while (0)
#define KSTEP0(t, buf) do { \
    f16x8 xf_; f32x4 A_ = xa[(t) % 5], B_ = xb[(t) % 5]; \
    xf_[0]=(_Float16)A_[0]; xf_[1]=(_Float16)A_[1]; xf_[2]=(_Float16)A_[2]; xf_[3]=(_Float16)A_[3]; \
    xf_[4]=(_Float16)B_[0]; xf_[5]=(_Float16)B_[1]; xf_[6]=(_Float16)B_[2]; xf_[7]=(_Float16)B_[3]; \
    kstep((buf), (t) & 3, lg1, e31, xf_, acc); } while (0)

  f32x16 acc[4];
  zero_acc(acc);
  f32x4 xa[5], xb[5];
  XISSUE(0); XISSUE(1); XISSUE(2); XISSUE(3); XISSUE(4);
  FENCE;
  VMWAIT(12); BARRIER;                       // slab0 landed (st1 + 10 x out)

  f16x8 fr[8];

  // ---------------- layer 0: slabs 0..5 (ring slot = s % 3) ----------------
  { const char* buf = lds;                                       // region 0
    stage(wt, 2, 2, lds, tid);
    KSTEP0(0, buf); XISSUE(5);
    KSTEP0(1, buf); XISSUE(6);
    KSTEP0(2, buf); XISSUE(7);
    KSTEP0(3, buf); XISSUE(8);
    VMWAIT(20); BARRIER; }
  { const char* buf = lds + 16384;                               // region 1
    stage(wt, 3, 0, lds, tid);
    KSTEP0(4, buf); XISSUE(9);
    KSTEP0(5, buf); XISSUE(10);
    KSTEP0(6, buf); XISSUE(11);
    KSTEP0(7, buf); XISSUE(12);
    VMWAIT(18); BARRIER; }
  { const char* buf = lds + 32768;                               // region 2
    stage(wt, 4, 1, lds, tid);
    KSTEP0(8, buf); XISSUE(13);
    KSTEP0(9, buf); XISSUE(14);
    KSTEP0(10, buf); XISSUE(15);
    KSTEP0(11, buf); XISSUE(16);
    VMWAIT(18); BARRIER; }
  { const char* buf = lds;                                       // region 3
    stage(wt, 5, 2, lds, tid);
    KSTEP0(12, buf); XISSUE(17);
    KSTEP0(13, buf); XISSUE(18);
    KSTEP0(14, buf); XISSUE(19);
    KSTEP0(15, buf); XISSUE(20);
    VMWAIT(18); BARRIER; }
  { const char* buf = lds + 16384;                               // region 4
    stage(wt, 6, 0, lds, tid);
    KSTEP0(16, buf); XISSUE(21);
    KSTEP0(17, buf); XISSUE(22);
    KSTEP0(18, buf); XISSUE(23);
    KSTEP0(19, buf);
    VMWAIT(16); BARRIER; }
  { const char* buf = lds + 32768;                               // region 5
    stage(wt, 7, 1, lds, tid);
    KSTEP0(20, buf);
    KSTEP0(21, buf);
    KSTEP0(22, buf);
    KSTEP0(23, buf);
    transition((const float*)(lds + 49152), lg1, acc, fr);       // b0 (LDS)
    zero_acc(acc);
    VMWAIT(8); BARRIER; }

  // ---------------- layer 1: slabs 6,7 ----------------
  { const char* buf = lds;                                       // region 6
    stage(wt, 8, 2, lds, tid);
    kstep(buf, 0, lg1, e31, fr[0], acc);
    kstep(buf, 1, lg1, e31, fr[1], acc);
    kstep(buf, 2, lg1, e31, fr[2], acc);
    kstep(buf, 3, lg1, e31, fr[3], acc);
    VMWAIT(2); BARRIER; }
  { const char* buf = lds + 16384;                               // region 7
    stage(wt, 9, 0, lds, tid);
    kstep(buf, 0, lg1, e31, fr[4], acc);
    kstep(buf, 1, lg1, e31, fr[5], acc);
    kstep(buf, 2, lg1, e31, fr[6], acc);
    kstep(buf, 3, lg1, e31, fr[7], acc);
    transition((const float*)(lds + 49152 + 512), lg1, acc, fr); // b1 (LDS)
    zero_acc(acc);
    VMWAIT(2); BARRIER; }

  // ---------------- layer 2: slabs 8,9 ----------------
  { const char* buf = lds + 32768;                               // region 8
    kstep(buf, 0, lg1, e31, fr[0], acc);
    kstep(buf, 1, lg1, e31, fr[1], acc);
    kstep(buf, 2, lg1, e31, fr[2], acc);
    kstep(buf, 3, lg1, e31, fr[3], acc);
    VMWAIT(0); BARRIER; }
  { const char* buf = lds;                                       // region 9
    kstep(buf, 0, lg1, e31, fr[4], acc);
    kstep(buf, 1, lg1, e31, fr[5], acc);
    kstep(buf, 2, lg1, e31, fr[6], acc);
    kstep(buf, 3, lg1, e31, fr[7], acc);
  }
  BARRIER;   // all ring reads done -> reuse ring LDS as transpose buffer

  // ---------------- bias + LayerNorm + transposed coalesced store ----------
  const float* pb2 = (const float*)(lds + 49152 + 1024);
  const float* pg  = (const float*)(lds + 49152 + 1536);
  const float* pbt = (const float*)(lds + 49152 + 2048);
  float sum = 0.f, sq = 0.f;
#pragma unroll
  for (int nt = 0; nt < 4; ++nt)
#pragma unroll
    for (int qq = 0; qq < 4; ++qq) {
      f32x4 bv = *(const f32x4*)(pb2 + nt * 32 + qq * 8 + 4 * lg1);
#pragma unroll
      for (int r = 0; r < 4; ++r) {
        float v = acc[nt][qq * 4 + r] + bv[r];
        acc[nt][qq * 4 + r] = v;
        sum += v; sq += v * v;
      }
    }
  sum += __shfl_xor(sum, 32, 64);
  sq  += __shfl_xor(sq, 32, 64);
  const float mu = sum * (1.0f / 128.0f);
  const float rs = rsqrtf(sq * (1.0f / 128.0f) - mu * mu + 1e-3f);

  float* T = (float*)lds + w * 1056;   // wave-private [32][33] f32
  const int l4 = lane >> 2, ch = lane & 3;
#pragma unroll
  for (int p = 0; p < 4; ++p) {
#pragma unroll
    for (int qq = 0; qq < 4; ++qq) {
      const int n0 = p * 32 + qq * 8 + 4 * lg1;
      f32x4 g4 = *(const f32x4*)(pg + n0);
      f32x4 t4 = *(const f32x4*)(pbt + n0);
#pragma unroll
      for (int r = 0; r < 4; ++r)
        T[e31 * 33 + qq * 8 + 4 * lg1 + r] =
            (acc[p][qq * 4 + r] - mu) * rs * g4[r] + t4[r];
    }
#pragma unroll
    for (int bb = 0; bb < 2; ++bb) {
      const int el = bb * 16 + l4;
      float* orow = out + (size_t)(eb + el) * 128 + p * 32 + ch * 4;
#pragma unroll
      for (int j = 0; j < 2; ++j) {
        f32x4 ov;
#pragma unroll
        for (int k = 0; k < 4; ++k) ov[k] = T[el * 33 + j * 16 + ch * 4 + k];
        *(f32x4*)(orow + j * 16) = ov;    // 16 rows x 64B contiguous / instr
      }
    }
  }
#undef XPTR
#undef XISSUE
#undef KSTEP0
}

extern "C" void kernel_launch(void* const* d_in, const int* in_sizes, int n_in,
                              void* d_out, int out_size, void* d_ws, size_t ws_size,
                              hipStream_t stream) {
  const float* sf    = (const float*)d_in[0];
  const float* rf    = (const float*)d_in[1];
  const float* ef    = (const float*)d_in[2];
  const int*   snd   = (const int*)d_in[3];
  const int*   rcv   = (const int*)d_in[4];
  const float* W0    = (const float*)d_in[5];
  const float* b0    = (const float*)d_in[6];
  const float* W1    = (const float*)d_in[7];
  const float* b1    = (const float*)d_in[8];
  const float* W2    = (const float*)d_in[9];
  const float* b2    = (const float*)d_in[10];
  const float* gamma = (const float*)d_in[11];
  const float* beta  = (const float*)d_in[12];
  short* wt = (short*)d_ws;   // 81920 shorts = 160KB swizzled fp16 image

  prep_weights<<<40, 256, 0, stream>>>(W0, W1, W2, wt);
  edge_mlp<<<1250, 512, 0, stream>>>(sf, rf, ef, snd, rcv, wt,
                                     b0, b1, b2, gamma, beta, (float*)d_out);
}

// Round 8
// 425.338 us; speedup vs baseline: 1.0375x; 1.0375x over previous
//
#include <hip/hip_runtime.h>
#include <stdint.h>

// ---------------------------------------------------------------------------
// MeshGraphNets edge processor, round 4 (5th submit — rounds 4-7 benches never
// ran: GPU acquisition timeouts; no counters produced).
//   gather+concat(384) -> 128 relu -> 128 relu -> 128 -> LayerNorm, E=320000.
//
// Round 2/3 post-mortem: REGISTER SPILLS (VGPR_Count=64 with a 64-reg
// accumulator + 80-192-reg x windows under a 128-reg launch-bounds cap).
// Scratch traffic explains the +150..265MB on FETCH and WRITE and the
// everything-idle profile (Mfma 9%, VALU 8%).
//
// Round 4:
//  * 256-thread blocks, __launch_bounds__(256,3): ~168-reg cap vs ~150 live.
//    LDS 48KB -> 3 blocks/CU -> 12 waves/CU, no spills.
//  * Plain __syncthreads (counted-vmcnt reverted: regression + fragile).
//    Ring-3, stage(slab r+2) issued right after region r's entry barrier.
//  * k-order rotated: edge_features (cold HBM stream) = t 0..7, issued from
//    the prologue; L2-resident sender/receiver gathers later. prep rotates
//    W0's k-axis by 128 to compensate.
//  * Weight-image swizzle gains a ((n>>3)&3) XOR term (both prep + read) to
//    break the 4-way bank conflict between lanes e31 = r mod 8.
//  * Verified round-2 math kept: swapped 32x32x16 orientation, pi=swap(b2,b3)
//    on W1/W2 k-axis, in-register transitions, LDS-transpose epilogue.
// ---------------------------------------------------------------------------

typedef __attribute__((ext_vector_type(8)))  short    s16x8;
typedef __attribute__((ext_vector_type(8)))  _Float16 f16x8;
typedef __attribute__((ext_vector_type(16))) float    f32x16;
typedef __attribute__((ext_vector_type(4)))  float    f32x4;

__device__ __forceinline__ f32x16 mfma16(f16x8 a, f16x8 b, f32x16 c) {
  return __builtin_amdgcn_mfma_f32_32x32x16_f16(a, b, c, 0, 0, 0);
}

// ---------------------------------------------------------------------------
// prep: W0[384][128], W1[128][128], W2[128][128] (fp32, k-major) -> fp16
// transposed swizzled slab images in d_ws.
// Image (shorts): slab*8192 + n*64 + ((kc ^ (n&7) ^ ((n>>3)&3)) * 8) + j.
// W0 k-source: ktrue = kslot<128 ? kslot+256 (edge) : kslot-128 (send|recv).
// W1/W2 k-source: pi = swap(bit2,bit3) of kslot (in-register transition).
// ---------------------------------------------------------------------------
__global__ void prep_weights(const float* __restrict__ W0,
                             const float* __restrict__ W1,
                             const float* __restrict__ W2,
                             short* __restrict__ ws) {
  int tid = blockIdx.x * 256 + threadIdx.x;        // 10240 threads
  const float* W;
  int rel, imgbase, kind;
  if (tid < 6144)      { W = W0; rel = tid;        imgbase = 0;     kind = 0; }
  else if (tid < 8192) { W = W1; rel = tid - 6144; imgbase = 49152; kind = 1; }
  else                 { W = W2; rel = tid - 8192; imgbase = 65536; kind = 1; }
  int n     = rel & 127;
  int chunk = rel >> 7;       // slab*8 + kc
  int slab  = chunk >> 3;
  int kc    = chunk & 7;
  s16x8 o;
#pragma unroll
  for (int j = 0; j < 8; ++j) {
    int kslot = slab * 64 + kc * 8 + j;
    int ktrue;
    if (kind == 0)               // W0: rotate blocks so edge feats are first
      ktrue = (kslot < 128) ? kslot + 256 : kslot - 128;
    else                         // W1/W2: pi = swap(bit2, bit3)
      ktrue = (kslot & ~12) | ((kslot & 4) << 1) | ((kslot & 8) >> 1);
    float v = W[(size_t)ktrue * 128 + n];
    o[j] = __builtin_bit_cast(short, (_Float16)v);
  }
  int slot = kc ^ (n & 7) ^ ((n >> 3) & 3);
  *(s16x8*)(ws + imgbase + slab * 8192 + n * 64 + (slot << 3)) = o;
}

// Stage one 16KB slab into an LDS ring slot (linear dest, swizzled source).
__device__ __forceinline__ void stage(const short* __restrict__ ws, int s,
                                      int slot, char* lds, int tid) {
  char* buf = lds + slot * 16384;
  const char* g = (const char*)ws + s * 16384;
#pragma unroll
  for (int i = 0; i < 4; ++i) {
    char* lp = buf + (i * 256 + (tid & ~63)) * 16;   // wave-uniform base
    const char* gp = g + (i * 256 + tid) * 16;       // per-lane source
    __builtin_amdgcn_global_load_lds(
        (__attribute__((address_space(1))) const void*)gp,
        (__attribute__((address_space(3))) void*)lp, 16, 0, 0);
  }
}

// One K=16 step: 4 output tiles, A = W^T fragment from swizzled LDS,
// B = xf (lane-resident activations).
__device__ __forceinline__ void kstep(const char* buf, int q, int lg1,
                                      int e31, f16x8 xf, f32x16* acc) {
  const int kc = q * 2 + lg1;
#pragma unroll
  for (int nt = 0; nt < 4; ++nt) {
    int n = nt * 32 + e31;
    int slot = kc ^ (e31 & 7) ^ ((e31 >> 3) & 3);
    s16x8 wf = *(const s16x8*)(buf + n * 128 + (slot << 4));
    acc[nt] = mfma16(__builtin_bit_cast(f16x8, wf), xf, acc[nt]);
  }
}

// bias + relu + cvt to fp16 B-fragments (verified round-2 mapping).
__device__ __forceinline__ void transition(const float* __restrict__ b,
                                           int lg1, f32x16* acc, f16x8* fr) {
#pragma unroll
  for (int ks = 0; ks < 8; ++ks) {
    const int nt = ks >> 1;
#pragma unroll
    for (int jq = 0; jq < 2; ++jq) {
      int nb = nt * 32 + 16 * (ks & 1) + 8 * jq + 4 * lg1;
      f32x4 bv = *(const f32x4*)(b + nb);
#pragma unroll
      for (int r = 0; r < 4; ++r) {
        float h = acc[nt][8 * (ks & 1) + jq * 4 + r] + bv[r];
        fr[ks][jq * 4 + r] = (_Float16)fmaxf(h, 0.0f);
      }
    }
  }
}

__device__ __forceinline__ void zero_acc(f32x16* acc) {
#pragma unroll
  for (int nt = 0; nt < 4; ++nt)
#pragma unroll
    for (int i = 0; i < 16; ++i) acc[nt][i] = 0.0f;
}

__global__ __launch_bounds__(256, 3) void edge_mlp(
    const float* __restrict__ sf, const float* __restrict__ rf,
    const float* __restrict__ ef, const int* __restrict__ snd,
    const int* __restrict__ rcv, const short* __restrict__ wt,
    const float* __restrict__ b0, const float* __restrict__ b1,
    const float* __restrict__ b2, const float* __restrict__ gamma,
    const float* __restrict__ beta, float* __restrict__ out) {
  __shared__ __align__(16) char lds[49152];          // 3 x 16KB ring
  const int tid  = threadIdx.x;
  const int w    = tid >> 6;
  const int lane = tid & 63;
  const int e31  = lane & 31;
  const int lg1  = lane >> 5;
  const int eb   = blockIdx.x * 128 + w * 32;
  const int e    = eb + e31;

  // ---- prologue ----
  const int sidx = snd[e];
  const int ridx = rcv[e];
  stage(wt, 0, 0, lds, tid);
  stage(wt, 1, 1, lds, tid);

  // t 0..7: edge feats (cold HBM stream, issued earliest)
  // t 8..15: sender gather; t 16..23: receiver gather (L2-resident tables)
  const float* xbase0 = ef + (size_t)e    * 128 + lg1 * 8;
  const float* xbase1 = sf + (size_t)sidx * 128 + lg1 * 8;
  const float* xbase2 = rf + (size_t)ridx * 128 + lg1 * 8;
#define XPTR(t) ((t) < 8 ? xbase0 + (t) * 16 \
                : (t) < 16 ? xbase1 + ((t) - 8) * 16 \
                : xbase2 + ((t) - 16) * 16)
#define XISSUE(t) do { const float* p_ = XPTR(t); \
    xa[(t) % 4] = *(const f32x4*)p_; xb[(t) % 4] = *(const f32x4*)(p_ + 4); } while (0)
#define KSTEP0(t, buf) do { \
    f16x8 xf_; f32x4 A_ = xa[(t) % 4], B_ = xb[(t) % 4]; \
    xf_[0]=(_Float16)A_[0]; xf_[1]=(_Float16)A_[1]; xf_[2]=(_Float16)A_[2]; xf_[3]=(_Float16)A_[3]; \
    xf_[4]=(_Float16)B_[0]; xf_[5]=(_Float16)B_[1]; xf_[6]=(_Float16)B_[2]; xf_[7]=(_Float16)B_[3]; \
    kstep((buf), (t) & 3, lg1, e31, xf_, acc); } while (0)

  f32x16 acc[4];
  zero_acc(acc);
  f32x4 xa[4], xb[4];
  XISSUE(0); XISSUE(1); XISSUE(2); XISSUE(3);
  f16x8 fr[8];

  // ---------- layer 0: regions 0..5 compute slab r at slot r%3 ----------
  __syncthreads();                                   // slabs 0,1 + x0..3 landed
  { const char* buf = lds;                           // region 0: slab 0
    stage(wt, 2, 2, lds, tid);
    KSTEP0(0, buf);  XISSUE(4);
    KSTEP0(1, buf);  XISSUE(5);
    KSTEP0(2, buf);  XISSUE(6);
    KSTEP0(3, buf);  XISSUE(7); }
  __syncthreads();
  { const char* buf = lds + 16384;                   // region 1: slab 1
    stage(wt, 3, 0, lds, tid);
    KSTEP0(4, buf);  XISSUE(8);
    KSTEP0(5, buf);  XISSUE(9);
    KSTEP0(6, buf);  XISSUE(10);
    KSTEP0(7, buf);  XISSUE(11); }
  __syncthreads();
  { const char* buf = lds + 32768;                   // region 2: slab 2
    stage(wt, 4, 1, lds, tid);
    KSTEP0(8, buf);  XISSUE(12);
    KSTEP0(9, buf);  XISSUE(13);
    KSTEP0(10, buf); XISSUE(14);
    KSTEP0(11, buf); XISSUE(15); }
  __syncthreads();
  { const char* buf = lds;                           // region 3: slab 3
    stage(wt, 5, 2, lds, tid);
    KSTEP0(12, buf); XISSUE(16);
    KSTEP0(13, buf); XISSUE(17);
    KSTEP0(14, buf); XISSUE(18);
    KSTEP0(15, buf); XISSUE(19); }
  __syncthreads();
  { const char* buf = lds + 16384;                   // region 4: slab 4
    stage(wt, 6, 0, lds, tid);
    KSTEP0(16, buf); XISSUE(20);
    KSTEP0(17, buf); XISSUE(21);
    KSTEP0(18, buf); XISSUE(22);
    KSTEP0(19, buf); XISSUE(23); }
  __syncthreads();
  { const char* buf = lds + 32768;                   // region 5: slab 5
    stage(wt, 7, 1, lds, tid);
    KSTEP0(20, buf);
    KSTEP0(21, buf);
    KSTEP0(22, buf);
    KSTEP0(23, buf);
    transition(b0, lg1, acc, fr);
    zero_acc(acc); }

  // ---------- layer 1: regions 6,7 (slabs 6,7) ----------
  __syncthreads();
  { const char* buf = lds;                           // region 6: slab 6
    stage(wt, 8, 2, lds, tid);
    kstep(buf, 0, lg1, e31, fr[0], acc);
    kstep(buf, 1, lg1, e31, fr[1], acc);
    kstep(buf, 2, lg1, e31, fr[2], acc);
    kstep(buf, 3, lg1, e31, fr[3], acc); }
  __syncthreads();
  { const char* buf = lds + 16384;                   // region 7: slab 7
    stage(wt, 9, 0, lds, tid);
    kstep(buf, 0, lg1, e31, fr[4], acc);
    kstep(buf, 1, lg1, e31, fr[5], acc);
    kstep(buf, 2, lg1, e31, fr[6], acc);
    kstep(buf, 3, lg1, e31, fr[7], acc);
    transition(b1, lg1, acc, fr);
    zero_acc(acc); }

  // ---------- layer 2: regions 8,9 (slabs 8,9) ----------
  __syncthreads();
  { const char* buf = lds + 32768;                   // region 8: slab 8
    kstep(buf, 0, lg1, e31, fr[0], acc);
    kstep(buf, 1, lg1, e31, fr[1], acc);
    kstep(buf, 2, lg1, e31, fr[2], acc);
    kstep(buf, 3, lg1, e31, fr[3], acc); }
  __syncthreads();
  { const char* buf = lds;                           // region 9: slab 9
    kstep(buf, 0, lg1, e31, fr[4], acc);
    kstep(buf, 1, lg1, e31, fr[5], acc);
    kstep(buf, 2, lg1, e31, fr[6], acc);
    kstep(buf, 3, lg1, e31, fr[7], acc); }
  __syncthreads();   // slots 1,2 fully read -> reuse as transpose buffer

  // ---------- bias + LayerNorm + transposed coalesced store ----------
  float sum = 0.f, sq = 0.f;
#pragma unroll
  for (int nt = 0; nt < 4; ++nt)
#pragma unroll
    for (int qq = 0; qq < 4; ++qq) {
      f32x4 bv = *(const f32x4*)(b2 + nt * 32 + qq * 8 + 4 * lg1);
#pragma unroll
      for (int r = 0; r < 4; ++r) {
        float v = acc[nt][qq * 4 + r] + bv[r];
        acc[nt][qq * 4 + r] = v;
        sum += v; sq += v * v;
      }
    }
  sum += __shfl_xor(sum, 32, 64);
  sq  += __shfl_xor(sq, 32, 64);
  const float mu = sum * (1.0f / 128.0f);
  const float rs = rsqrtf(sq * (1.0f / 128.0f) - mu * mu + 1e-3f);

  float* T = (float*)(lds + 16384) + w * 1056;       // wave-private [32][33]
  const int l4 = lane >> 2, ch = lane & 3;
#pragma unroll
  for (int p = 0; p < 4; ++p) {
#pragma unroll
    for (int qq = 0; qq < 4; ++qq) {
      const int n0 = p * 32 + qq * 8 + 4 * lg1;
      f32x4 g4 = *(const f32x4*)(gamma + n0);
      f32x4 t4 = *(const f32x4*)(beta + n0);
#pragma unroll
      for (int r = 0; r < 4; ++r)
        T[e31 * 33 + qq * 8 + 4 * lg1 + r] =
            (acc[p][qq * 4 + r] - mu) * rs * g4[r] + t4[r];
    }
#pragma unroll
    for (int bb = 0; bb < 2; ++bb) {
      const int el = bb * 16 + l4;
      float* orow = out + (size_t)(eb + el) * 128 + p * 32 + ch * 4;
#pragma unroll
      for (int j = 0; j < 2; ++j) {
        f32x4 ov;
#pragma unroll
        for (int k = 0; k < 4; ++k) ov[k] = T[el * 33 + j * 16 + ch * 4 + k];
        *(f32x4*)(orow + j * 16) = ov;    // 16 rows x 64B contiguous / instr
      }
    }
  }
#undef XPTR
#undef XISSUE
#undef KSTEP0
}

extern "C" void kernel_launch(void* const* d_in, const int* in_sizes, int n_in,
                              void* d_out, int out_size, void* d_ws, size_t ws_size,
                              hipStream_t stream) {
  const float* sf    = (const float*)d_in[0];
  const float* rf    = (const float*)d_in[1];
  const float* ef    = (const float*)d_in[2];
  const int*   snd   = (const int*)d_in[3];
  const int*   rcv   = (const int*)d_in[4];
  const float* W0    = (const float*)d_in[5];
  const float* b0    = (const float*)d_in[6];
  const float* W1    = (const float*)d_in[7];
  const float* b1    = (const float*)d_in[8];
  const float* W2    = (const float*)d_in[9];
  const float* b2    = (const float*)d_in[10];
  const float* gamma = (const float*)d_in[11];
  const float* beta  = (const float*)d_in[12];
  short* wt = (short*)d_ws;   // 81920 shorts = 160KB swizzled fp16 image

  prep_weights<<<40, 256, 0, stream>>>(W0, W1, W2, wt);
  edge_mlp<<<2500, 256, 0, stream>>>(sf, rf, ef, snd, rcv, wt,
                                     b0, b1, b2, gamma, beta, (float*)d_out);
}